// Round 5
// baseline (295.709 us; speedup 1.0000x reference)
//
#include <hip/hip_runtime.h>

#define N_NEUR 512
#define B_SZ   16
#define T_STEPS 32
#define NIN    32
#define NOUT   16
#define CAPC   84   // chem nnz/row cap (mean 48.6, sd 6.63)
#define CAPG   52   // gj nnz/row cap   (mean 25.6, sd 4.93)
#define MC     42   // per-thread chem entries (h splits CSR evens/odds)
#define MG     26
#define MCP    21   // packed col words per thread
#define MGP    13
#define LOG2E  1.4426950408889634f

__device__ __forceinline__ float rcp_fast(float x) {
#if __has_builtin(__builtin_amdgcn_rcpf)
    return __builtin_amdgcn_rcpf(x);
#else
    return 1.0f / x;
#endif
}
__device__ __forceinline__ float exp2_fast(float x) {
#if __has_builtin(__builtin_amdgcn_exp2f)
    return __builtin_amdgcn_exp2f(x);
#else
    return exp2f(x);
#endif
}

// prep1: per row, softplus + mask + ballot-compact into dense per-row tmp CSR.
__global__ __launch_bounds__(64) void prep1_kernel(
    const float* __restrict__ W,
    const float* __restrict__ mex,
    const float* __restrict__ min_,
    const float* __restrict__ mgj,
    int* __restrict__ key_arr, int* __restrict__ ccA, int* __restrict__ cgA,
    int2* __restrict__ tmpC, int2* __restrict__ tmpG)
{
    const int row  = blockIdx.x;
    const int lane = threadIdx.x;
    const unsigned long long below = (1ull << lane) - 1ull;
    int bc = 0, bg = 0;
    for (int c0 = 0; c0 < N_NEUR; c0 += 64) {
        const int col = c0 + lane;
        const int off = row * N_NEUR + col;
        const float w  = W[off];
        const float sp = fmaxf(w, 0.0f) + log1pf(__expf(-fabsf(w)));  // softplus
        const float dm = mex[off] - min_[off];                         // in {-1,0,1}
        bool a = (dm != 0.0f);
        unsigned long long m = __ballot(a);
        int idx = bc + __popcll(m & below);
        if (a && idx < CAPC)
            tmpC[row * CAPC + idx] = make_int2(col, __float_as_int(sp * dm));
        bc += __popcll(m);

        const float g = mgj[off];
        bool ag = (g != 0.0f);
        m = __ballot(ag);
        idx = bg + __popcll(m & below);
        if (ag && idx < CAPG)
            tmpG[row * CAPG + idx] = make_int2(col, __float_as_int(sp * g));
        bg += __popcll(m);
    }
    if (lane == 0) {
        int cc = min(bc, CAPC), cg = min(bg, CAPG);
        ccA[row] = cc; cgA[row] = cg; key_arr[row] = cc + cg;
    }
}

// prep2: rank rows by nnz (asc); split each row's CSR into evens/odds (h),
// BANK-STAGGER sort each thread's list by ((col&31) - mainLane) & 31 so that
// slot k of the 64 lanes forms a staircase across LDS banks (cuts conflicts),
// then emit transposed zero-padded layout for the main kernel's register
// loads: wT[(wv*M + k)*64 + lane], packed byte-scaled col pairs in cT.
__global__ __launch_bounds__(64) void prep2_kernel(
    const int* __restrict__ key_arr, const int* __restrict__ ccA, const int* __restrict__ cgA,
    const int2* __restrict__ tmpC, const int2* __restrict__ tmpG,
    int* __restrict__ order,
    float* __restrict__ wCt, unsigned* __restrict__ cpCt,
    float* __restrict__ wGt, unsigned* __restrict__ cpGt)
{
    __shared__ int   cS[CAPC];  __shared__ float wS[CAPC];
    __shared__ int   cSg[CAPG]; __shared__ float wSg[CAPG];
    const int d    = blockIdx.x;
    const int lane = threadIdx.x;
    const int kd   = key_arr[d];
    int r = 0;
    for (int j = lane; j < N_NEUR; j += 64) {
        int kj = key_arr[j];
        r += (kj < kd) || (kj == kd && j < d);
    }
    #pragma unroll
    for (int i = 1; i < 64; i <<= 1) r += __shfl_xor(r, i);
    if (lane == 0) order[r] = d;

    const int wv = r >> 5;            // main tid = 2r+h -> wv = r>>5
    const int Lb = 2 * (r & 31);
    const int cc = ccA[d], cg = cgA[d];

    for (int k = lane; k < CAPC; k += 64) {
        int2 e = (k < cc) ? tmpC[d * CAPC + k] : make_int2(0, 0);
        cS[k] = e.x; wS[k] = __int_as_float(e.y);
    }
    for (int k = lane; k < CAPG; k += 64) {
        int2 e = (k < cg) ? tmpG[d * CAPG + k] : make_int2(0, 0);
        cSg[k] = e.x; wSg[k] = __int_as_float(e.y);
    }
    __syncthreads();

    if (lane < 4) {                    // 4 serial tasks: {chem,gj} x {h0,h1}
        const int isG = lane >> 1, h = lane & 1;
        const int cnt = isG ? cg : cc;
        const int M   = isG ? MG : MC;
        const int MP  = isG ? MGP : MCP;
        const int myL = Lb + h;        // this thread's lane in the main kernel
        int cols[MC]; float ws[MC];
        int m = 0;
        for (int s = h; s < cnt; s += 2) {
            cols[m] = isG ? cSg[s] : cS[s];
            ws[m]   = isG ? wSg[s] : wS[s];
            ++m;
        }
        for (int i = 1; i < m; ++i) {  // insertion sort by stagger key
            int c = cols[i]; float w = ws[i];
            int key = ((c & 31) - myL) & 31;
            int j = i - 1;
            while (j >= 0 && ((((cols[j] & 31) - myL) & 31) > key)) {
                cols[j + 1] = cols[j]; ws[j + 1] = ws[j]; --j;
            }
            cols[j + 1] = c; ws[j + 1] = w;
        }
        float*    wT = isG ? wGt  : wCt;
        unsigned* cT = isG ? cpGt : cpCt;
        for (int k = 0; k < M; ++k)
            wT[(wv * M + k) * 64 + myL] = (k < m) ? ws[k] : 0.0f;
        for (int kp = 0; kp < MP; ++kp) {
            unsigned c0 = (2 * kp     < m) ? ((unsigned)cols[2 * kp]     << 2) : 0u;
            unsigned c1 = (2 * kp + 1 < m) ? ((unsigned)cols[2 * kp + 1] << 2) : 0u;
            cT[(wv * MP + kp) * 64 + myL] = c0 | (c1 << 16);
        }
    }
}

#define CHEM_K(k, A) {                                                      \
    unsigned pk = cpC[(k) >> 1];                                            \
    unsigned off = ((k) & 1) ? (pk >> 16) : (pk & 0xffffu);                 \
    A = fmaf(wC[k], *(const float*)((const char*)ObP + off), A); }

#define CHEM_C4(a) { CHEM_K(a, accA) CHEM_K((a)+1, accB) CHEM_K((a)+2, accA) CHEM_K((a)+3, accB) }

#define GJ_K(k, A) {                                                        \
    unsigned pk = cpG[(k) >> 1];                                            \
    unsigned off = ((k) & 1) ? (pk >> 16) : (pk & 0xffffu);                 \
    float Os = *(const float*)((const char*)ObP + off);                     \
    float f = fmaf(20.0f * LOG2E, Os, cE);                                  \
    float tnh = 1.0f - 2.0f * rcp_fast(1.0f + exp2_fast(f));                \
    A = fmaf(wG[k] * Os, tnh, A); }

#define GJ_C4(a) { GJ_K(a, accA) GJ_K((a)+1, accB) GJ_K((a)+2, accA) GJ_K((a)+3, accB) }

// main: one block per batch, 1024 threads = 2 per neuron (sorted by nnz).
// Lists in registers/AGPRs; fixed-trip unrolled chunks with wave-uniform
// scalar guards (granularity 4); ONE barrier per step (obs injection folded
// into the write phase: writing obs_{t+1} at step t's end == reference's
// pre-compute set at step t+1; the reference's post-set is overwritten and
// outputs (d in [32,48)) don't overlap inputs (d<32)).
__global__ __launch_bounds__(1024, 1) void recur_kernel(
    const float* __restrict__ obs,
    const float* __restrict__ thr,
    const float* __restrict__ dec,
    const int* __restrict__ order, const int* __restrict__ ccA, const int* __restrict__ cgA,
    const float* __restrict__ wCt, const unsigned* __restrict__ cpCt,
    const float* __restrict__ wGt, const unsigned* __restrict__ cpGt,
    float* __restrict__ out)
{
    __shared__ float Ob[2][N_NEUR];
    __shared__ float Eb[2][N_NEUR];

    const int b    = blockIdx.x;
    const int tid  = threadIdx.x;
    const int h    = tid & 1;
    const int r    = tid >> 1;            // rank
    const int wv   = tid >> 6;
    const int lane = tid & 63;

    const int d = order[r];
    const int cc = ccA[d];
    const int cg = cgA[d];
    const float thr_d = thr[d];
    const float dec_d = dec[d];

    int ccw = cc, cgw = cg;
    #pragma unroll
    for (int i = 1; i < 64; i <<= 1) {
        ccw = max(ccw, __shfl_xor(ccw, i));
        cgw = max(cgw, __shfl_xor(cgw, i));
    }
    const int mCw = __builtin_amdgcn_readfirstlane((ccw + 1) >> 1);
    const int mGw = __builtin_amdgcn_readfirstlane((cgw + 1) >> 1);

    // register-resident lists (zero-padded; padding cols are 0 -> broadcast)
    float wC[MC]; unsigned cpC[MCP];
    float wG[MG]; unsigned cpG[MGP];
    #pragma unroll
    for (int k = 0; k < MC; ++k)  wC[k]  = wCt[(wv * MC + k) * 64 + lane];
    #pragma unroll
    for (int k = 0; k < MCP; ++k) cpC[k] = cpCt[(wv * MCP + k) * 64 + lane];
    #pragma unroll
    for (int k = 0; k < MG; ++k)  wG[k]  = wGt[(wv * MG + k) * 64 + lane];
    #pragma unroll
    for (int k = 0; k < MGP; ++k) cpG[k] = cpGt[(wv * MGP + k) * 64 + lane];

    const bool inj = (h == 0) && (d < NIN);
    const bool wr  = (h == 0) && (d >= NIN) && (d < NIN + NOUT);
    float* outp = out + (size_t)b * T_STEPS * NOUT + (d - NIN);
    const float* obs_b = obs + b * (T_STEPS * NIN);

    if (h == 0) {
        float v = (d < NIN) ? obs_b[d] : 0.0f;   // state 0 = zeros + obs_0
        Ob[0][d] = v;
        Eb[0][d] = v;
    }
    int p = 0;
    __syncthreads();

    for (int t = 0; t < T_STEPS; ++t) {
        // prefetch obs_{t+1} (written into the next buffer at this step's end)
        float ob_next = (inj && (t + 1 < T_STEPS)) ? obs_b[(t + 1) * NIN + d] : 0.0f;

        const float* ObP = Ob[p];
        const float E_d = Eb[p][d];
        float accA = 0.0f, accB = 0.0f;
        // chem: chunks of 4, wave-uniform scalar guards, constant reg indices
        CHEM_C4(0)
        if ( 4 < mCw) CHEM_C4(4)
        if ( 8 < mCw) CHEM_C4(8)
        if (12 < mCw) CHEM_C4(12)
        if (16 < mCw) CHEM_C4(16)
        if (20 < mCw) CHEM_C4(20)
        if (24 < mCw) CHEM_C4(24)
        if (28 < mCw) CHEM_C4(28)
        if (32 < mCw) CHEM_C4(32)
        if (36 < mCw) CHEM_C4(36)
        if (40 < mCw) { CHEM_K(40, accA) CHEM_K(41, accB) }
        // gj
        const float cE = -20.0f * LOG2E * E_d;
        GJ_C4(0)
        if ( 4 < mGw) GJ_C4(4)
        if ( 8 < mGw) GJ_C4(8)
        if (12 < mGw) GJ_C4(12)
        if (16 < mGw) GJ_C4(16)
        if (20 < mGw) GJ_C4(20)
        if (24 < mGw) { GJ_K(24, accA) GJ_K(25, accB) }

        float acc = accA + accB;
        acc += __shfl_xor(acc, 1);

        // epilogue (both halves compute; h==0 writes)
        float curr = fminf(fmaxf(E_d + acc, -10.0f), 10.0f);
        float z = curr - thr_d;
        float O_new = (z >= 0.0f) ? z : 0.01f * z;
        float fg = rcp_fast(1.0f + exp2_fast(-10.0f * LOG2E * z));
        float dg = rcp_fast(1.0f + exp2_fast(-5.0f * LOG2E * (fabsf(E_d - curr) - 0.01f)));
        float E_nf  = dg * curr + (1.0f - dg) * (E_d - dec_d);
        float E_new = fg * O_new + (1.0f - fg) * E_nf;

        const int q = p ^ 1;
        if (h == 0) {
            Eb[q][d] = inj ? ob_next : E_new;
            Ob[q][d] = inj ? ob_next : O_new;
            if (wr) outp[t * NOUT] = E_new;
        }
        __syncthreads();
        p = q;
    }
}

extern "C" void kernel_launch(void* const* d_in, const int* in_sizes, int n_in,
                              void* d_out, int out_size, void* d_ws, size_t ws_size,
                              hipStream_t stream)
{
    const float* obs  = (const float*)d_in[0];
    const float* W    = (const float*)d_in[1];
    const float* thr  = (const float*)d_in[2];
    const float* dec  = (const float*)d_in[3];
    const float* mex  = (const float*)d_in[4];
    const float* min_ = (const float*)d_in[5];
    const float* mgj  = (const float*)d_in[6];
    float* out = (float*)d_out;

    char* ws = (char*)d_ws;
    int*   key_arr = (int*)(ws);
    int*   ccA     = (int*)(ws + 2048);
    int*   cgA     = (int*)(ws + 4096);
    int*   order   = (int*)(ws + 6144);
    int2*  tmpC    = (int2*)(ws + 8192);                   // 512*84*8 = 344064
    int2*  tmpG    = (int2*)(ws + 8192 + 344064);          // 512*52*8 = 212992
    float* wCt     = (float*)(ws + 565248);                // 16*42*64*4 = 172032
    unsigned* cpCt = (unsigned*)(ws + 737280);             // 16*21*64*4 =  86016
    float* wGt     = (float*)(ws + 823296);                // 16*26*64*4 = 106496
    unsigned* cpGt = (unsigned*)(ws + 929792);             // 16*13*64*4 =  53248
    // total ws use: ~983 KB

    prep1_kernel<<<N_NEUR, 64, 0, stream>>>(W, mex, min_, mgj,
                                            key_arr, ccA, cgA, tmpC, tmpG);
    prep2_kernel<<<N_NEUR, 64, 0, stream>>>(key_arr, ccA, cgA, tmpC, tmpG,
                                            order, wCt, cpCt, wGt, cpGt);
    recur_kernel<<<B_SZ, 1024, 0, stream>>>(obs, thr, dec,
                                            order, ccA, cgA,
                                            wCt, cpCt, wGt, cpGt, out);
}

// Round 6
// 184.545 us; speedup vs baseline: 1.6024x; 1.6024x over previous
//
#include <hip/hip_runtime.h>

#define N_NEUR 512
#define B_SZ   16
#define T_STEPS 32
#define NIN    32
#define NOUT   16
#define CAPC   84   // chem nnz/row cap (mean 48.6, sd 6.63)
#define CAPG   52   // gj nnz/row cap   (mean 25.6, sd 4.93)
#define MC     42   // per-thread chem entries (h splits CSR evens/odds)
#define MG     26
#define MCP    21   // packed col words per thread
#define MGP    13
#define LOG2E  1.4426950408889634f

__device__ __forceinline__ float rcp_fast(float x) {
#if __has_builtin(__builtin_amdgcn_rcpf)
    return __builtin_amdgcn_rcpf(x);
#else
    return 1.0f / x;
#endif
}
__device__ __forceinline__ float exp2_fast(float x) {
#if __has_builtin(__builtin_amdgcn_exp2f)
    return __builtin_amdgcn_exp2f(x);
#else
    return exp2f(x);
#endif
}

// prep1: per row, softplus + mask + ballot-compact into dense per-row tmp CSR.
__global__ __launch_bounds__(64) void prep1_kernel(
    const float* __restrict__ W,
    const float* __restrict__ mex,
    const float* __restrict__ min_,
    const float* __restrict__ mgj,
    int* __restrict__ key_arr, int* __restrict__ ccA, int* __restrict__ cgA,
    int2* __restrict__ tmpC, int2* __restrict__ tmpG)
{
    const int row  = blockIdx.x;
    const int lane = threadIdx.x;
    const unsigned long long below = (1ull << lane) - 1ull;
    int bc = 0, bg = 0;
    for (int c0 = 0; c0 < N_NEUR; c0 += 64) {
        const int col = c0 + lane;
        const int off = row * N_NEUR + col;
        const float w  = W[off];
        const float sp = fmaxf(w, 0.0f) + log1pf(__expf(-fabsf(w)));  // softplus
        const float dm = mex[off] - min_[off];                         // in {-1,0,1}
        bool a = (dm != 0.0f);
        unsigned long long m = __ballot(a);
        int idx = bc + __popcll(m & below);
        if (a && idx < CAPC)
            tmpC[row * CAPC + idx] = make_int2(col, __float_as_int(sp * dm));
        bc += __popcll(m);

        const float g = mgj[off];
        bool ag = (g != 0.0f);
        m = __ballot(ag);
        idx = bg + __popcll(m & below);
        if (ag && idx < CAPG)
            tmpG[row * CAPG + idx] = make_int2(col, __float_as_int(sp * g));
        bg += __popcll(m);
    }
    if (lane == 0) {
        int cc = min(bc, CAPC), cg = min(bg, CAPG);
        ccA[row] = cc; cgA[row] = cg; key_arr[row] = cc + cg;
    }
}

// prep2: rank rows by nnz (asc); split each row's CSR into evens/odds (h),
// BANK-STAGGER sort each thread's list by ((col&31) - mainLane) & 31 via a
// PARALLEL RANK SORT in LDS (round-5's per-thread insertion sort spilled to
// scratch: 119us, 2.2MB writes). Lane k owns entry k; rank = #{(key_j,j) <
// (key_k,k)}; scatter to sorted LDS arrays; emit transposed layout
// wT[(wv*M + k)*64 + lane], packed byte-scaled col pairs in cT.
__global__ __launch_bounds__(64) void prep2_kernel(
    const int* __restrict__ key_arr, const int* __restrict__ ccA, const int* __restrict__ cgA,
    const int2* __restrict__ tmpC, const int2* __restrict__ tmpG,
    int* __restrict__ order,
    float* __restrict__ wCt, unsigned* __restrict__ cpCt,
    float* __restrict__ wGt, unsigned* __restrict__ cpGt)
{
    __shared__ int   cS[CAPC];  __shared__ float wS[CAPC];
    __shared__ int   cSg[CAPG]; __shared__ float wSg[CAPG];
    __shared__ int   keyS[MC];
    __shared__ int   scol[MC];  __shared__ float sw[MC];
    const int d    = blockIdx.x;
    const int lane = threadIdx.x;
    const int kd   = key_arr[d];
    int r = 0;
    for (int j = lane; j < N_NEUR; j += 64) {
        int kj = key_arr[j];
        r += (kj < kd) || (kj == kd && j < d);
    }
    #pragma unroll
    for (int i = 1; i < 64; i <<= 1) r += __shfl_xor(r, i);
    if (lane == 0) order[r] = d;

    const int wv = r >> 5;            // main tid = 2r+h -> wv = r>>5
    const int Lb = 2 * (r & 31);
    const int cc = ccA[d], cg = cgA[d];

    for (int k = lane; k < CAPC; k += 64) {
        int2 e = (k < cc) ? tmpC[d * CAPC + k] : make_int2(0, 0);
        cS[k] = e.x; wS[k] = __int_as_float(e.y);
    }
    for (int k = lane; k < CAPG; k += 64) {
        int2 e = (k < cg) ? tmpG[d * CAPG + k] : make_int2(0, 0);
        cSg[k] = e.x; wSg[k] = __int_as_float(e.y);
    }
    __syncthreads();

    #pragma unroll
    for (int task = 0; task < 4; ++task) {   // {chem,gj} x {h0,h1}
        const int isG = task >> 1, h = task & 1;
        const int cnt = isG ? cg : cc;
        const int m   = (cnt + 1 - h) >> 1;  // entries in this half-list
        const int M   = isG ? MG : MC;
        const int MP  = isG ? MGP : MCP;
        const int myL = Lb + h;              // owner lane in the main kernel

        int col = 0; float w = 0.0f; int key = 0;
        if (lane < m) {                      // lane k owns CSR entry 2k+h
            col = isG ? cSg[2 * lane + h] : cS[2 * lane + h];
            w   = isG ? wSg[2 * lane + h] : wS[2 * lane + h];
            key = ((col & 31) - myL) & 31;
            keyS[lane] = key;
        }
        __syncthreads();
        if (lane < m) {
            int rk = 0;
            for (int j = 0; j < m; ++j) {
                int kj = keyS[j];
                rk += (kj < key) || (kj == key && j < lane);
            }
            scol[rk] = col; sw[rk] = w;
        }
        __syncthreads();
        float*    wT = isG ? wGt  : wCt;
        unsigned* cT = isG ? cpGt : cpCt;
        if (lane < M)
            wT[(wv * M + lane) * 64 + myL] = (lane < m) ? sw[lane] : 0.0f;
        if (lane < MP) {
            unsigned c0 = (2 * lane     < m) ? ((unsigned)scol[2 * lane]     << 2) : 0u;
            unsigned c1 = (2 * lane + 1 < m) ? ((unsigned)scol[2 * lane + 1] << 2) : 0u;
            cT[(wv * MP + lane) * 64 + myL] = c0 | (c1 << 16);
        }
        __syncthreads();                     // scol/keyS reused next task
    }
}

#define CHEM_K(k, A) {                                                      \
    unsigned pk = cpC[(k) >> 1];                                            \
    unsigned off = ((k) & 1) ? (pk >> 16) : (pk & 0xffffu);                 \
    A = fmaf(wC[k], *(const float*)((const char*)ObP + off), A); }

#define CHEM_C4(a) { CHEM_K(a, accA) CHEM_K((a)+1, accB) CHEM_K((a)+2, accA) CHEM_K((a)+3, accB) }

#define GJ_K(k, A) {                                                        \
    unsigned pk = cpG[(k) >> 1];                                            \
    unsigned off = ((k) & 1) ? (pk >> 16) : (pk & 0xffffu);                 \
    float Os = *(const float*)((const char*)ObP + off);                     \
    float f = fmaf(20.0f * LOG2E, Os, cE);                                  \
    float tnh = 1.0f - 2.0f * rcp_fast(1.0f + exp2_fast(f));                \
    A = fmaf(wG[k] * Os, tnh, A); }

#define GJ_C4(a) { GJ_K(a, accA) GJ_K((a)+1, accB) GJ_K((a)+2, accA) GJ_K((a)+3, accB) }

// main: one block per batch, 1024 threads = 2 per neuron (sorted by nnz).
// Lists in registers/AGPRs; fixed-trip unrolled chunks with wave-uniform
// scalar guards (granularity 4); ONE barrier per step (obs injection folded
// into the write phase).
__global__ __launch_bounds__(1024, 1) void recur_kernel(
    const float* __restrict__ obs,
    const float* __restrict__ thr,
    const float* __restrict__ dec,
    const int* __restrict__ order, const int* __restrict__ ccA, const int* __restrict__ cgA,
    const float* __restrict__ wCt, const unsigned* __restrict__ cpCt,
    const float* __restrict__ wGt, const unsigned* __restrict__ cpGt,
    float* __restrict__ out)
{
    __shared__ float Ob[2][N_NEUR];
    __shared__ float Eb[2][N_NEUR];

    const int b    = blockIdx.x;
    const int tid  = threadIdx.x;
    const int h    = tid & 1;
    const int r    = tid >> 1;            // rank
    const int wv   = tid >> 6;
    const int lane = tid & 63;

    const int d = order[r];
    const int cc = ccA[d];
    const int cg = cgA[d];
    const float thr_d = thr[d];
    const float dec_d = dec[d];

    int ccw = cc, cgw = cg;
    #pragma unroll
    for (int i = 1; i < 64; i <<= 1) {
        ccw = max(ccw, __shfl_xor(ccw, i));
        cgw = max(cgw, __shfl_xor(cgw, i));
    }
    const int mCw = __builtin_amdgcn_readfirstlane((ccw + 1) >> 1);
    const int mGw = __builtin_amdgcn_readfirstlane((cgw + 1) >> 1);

    // register-resident lists (zero-padded; padding cols are 0 -> broadcast)
    float wC[MC]; unsigned cpC[MCP];
    float wG[MG]; unsigned cpG[MGP];
    #pragma unroll
    for (int k = 0; k < MC; ++k)  wC[k]  = wCt[(wv * MC + k) * 64 + lane];
    #pragma unroll
    for (int k = 0; k < MCP; ++k) cpC[k] = cpCt[(wv * MCP + k) * 64 + lane];
    #pragma unroll
    for (int k = 0; k < MG; ++k)  wG[k]  = wGt[(wv * MG + k) * 64 + lane];
    #pragma unroll
    for (int k = 0; k < MGP; ++k) cpG[k] = cpGt[(wv * MGP + k) * 64 + lane];

    const bool inj = (h == 0) && (d < NIN);
    const bool wr  = (h == 0) && (d >= NIN) && (d < NIN + NOUT);
    float* outp = out + (size_t)b * T_STEPS * NOUT + (d - NIN);
    const float* obs_b = obs + b * (T_STEPS * NIN);

    if (h == 0) {
        float v = (d < NIN) ? obs_b[d] : 0.0f;   // state 0 = zeros + obs_0
        Ob[0][d] = v;
        Eb[0][d] = v;
    }
    int p = 0;
    __syncthreads();

    for (int t = 0; t < T_STEPS; ++t) {
        // prefetch obs_{t+1} (written into the next buffer at this step's end)
        float ob_next = (inj && (t + 1 < T_STEPS)) ? obs_b[(t + 1) * NIN + d] : 0.0f;

        const float* ObP = Ob[p];
        const float E_d = Eb[p][d];
        float accA = 0.0f, accB = 0.0f;
        // chem: chunks of 4, wave-uniform scalar guards, constant reg indices
        CHEM_C4(0)
        if ( 4 < mCw) CHEM_C4(4)
        if ( 8 < mCw) CHEM_C4(8)
        if (12 < mCw) CHEM_C4(12)
        if (16 < mCw) CHEM_C4(16)
        if (20 < mCw) CHEM_C4(20)
        if (24 < mCw) CHEM_C4(24)
        if (28 < mCw) CHEM_C4(28)
        if (32 < mCw) CHEM_C4(32)
        if (36 < mCw) CHEM_C4(36)
        if (40 < mCw) { CHEM_K(40, accA) CHEM_K(41, accB) }
        // gj
        const float cE = -20.0f * LOG2E * E_d;
        GJ_C4(0)
        if ( 4 < mGw) GJ_C4(4)
        if ( 8 < mGw) GJ_C4(8)
        if (12 < mGw) GJ_C4(12)
        if (16 < mGw) GJ_C4(16)
        if (20 < mGw) GJ_C4(20)
        if (24 < mGw) { GJ_K(24, accA) GJ_K(25, accB) }

        float acc = accA + accB;
        acc += __shfl_xor(acc, 1);

        // epilogue (both halves compute; h==0 writes)
        float curr = fminf(fmaxf(E_d + acc, -10.0f), 10.0f);
        float z = curr - thr_d;
        float O_new = (z >= 0.0f) ? z : 0.01f * z;
        float fg = rcp_fast(1.0f + exp2_fast(-10.0f * LOG2E * z));
        float dg = rcp_fast(1.0f + exp2_fast(-5.0f * LOG2E * (fabsf(E_d - curr) - 0.01f)));
        float E_nf  = dg * curr + (1.0f - dg) * (E_d - dec_d);
        float E_new = fg * O_new + (1.0f - fg) * E_nf;

        const int q = p ^ 1;
        if (h == 0) {
            Eb[q][d] = inj ? ob_next : E_new;
            Ob[q][d] = inj ? ob_next : O_new;
            if (wr) outp[t * NOUT] = E_new;
        }
        __syncthreads();
        p = q;
    }
}

extern "C" void kernel_launch(void* const* d_in, const int* in_sizes, int n_in,
                              void* d_out, int out_size, void* d_ws, size_t ws_size,
                              hipStream_t stream)
{
    const float* obs  = (const float*)d_in[0];
    const float* W    = (const float*)d_in[1];
    const float* thr  = (const float*)d_in[2];
    const float* dec  = (const float*)d_in[3];
    const float* mex  = (const float*)d_in[4];
    const float* min_ = (const float*)d_in[5];
    const float* mgj  = (const float*)d_in[6];
    float* out = (float*)d_out;

    char* ws = (char*)d_ws;
    int*   key_arr = (int*)(ws);
    int*   ccA     = (int*)(ws + 2048);
    int*   cgA     = (int*)(ws + 4096);
    int*   order   = (int*)(ws + 6144);
    int2*  tmpC    = (int2*)(ws + 8192);                   // 512*84*8 = 344064
    int2*  tmpG    = (int2*)(ws + 8192 + 344064);          // 512*52*8 = 212992
    float* wCt     = (float*)(ws + 565248);                // 16*42*64*4 = 172032
    unsigned* cpCt = (unsigned*)(ws + 737280);             // 16*21*64*4 =  86016
    float* wGt     = (float*)(ws + 823296);                // 16*26*64*4 = 106496
    unsigned* cpGt = (unsigned*)(ws + 929792);             // 16*13*64*4 =  53248
    // total ws use: ~983 KB

    prep1_kernel<<<N_NEUR, 64, 0, stream>>>(W, mex, min_, mgj,
                                            key_arr, ccA, cgA, tmpC, tmpG);
    prep2_kernel<<<N_NEUR, 64, 0, stream>>>(key_arr, ccA, cgA, tmpC, tmpG,
                                            order, wCt, cpCt, wGt, cpGt);
    recur_kernel<<<B_SZ, 1024, 0, stream>>>(obs, thr, dec,
                                            order, ccA, cgA,
                                            wCt, cpCt, wGt, cpGt, out);
}